// Round 1
// baseline (192.570 us; speedup 1.0000x reference)
//
#include <hip/hip_runtime.h>
#include <stdint.h>

typedef __attribute__((ext_vector_type(4))) float f32x4;
typedef __attribute__((ext_vector_type(8))) short s16x8;
typedef __attribute__((ext_vector_type(8))) __bf16 bf16x8;

#define SCALE 0.17677669529663687f  // 32^-0.5

__device__ __forceinline__ unsigned f2bf(float f) {
  unsigned u = __builtin_bit_cast(unsigned, f);
  u += 0x7fffu + ((u >> 16) & 1u);   // RNE
  return u >> 16;
}

__device__ __forceinline__ f32x4 MFMA(s16x8 a, s16x8 b, f32x4 c) {
  return __builtin_amdgcn_mfma_f32_16x16x32_bf16(
      __builtin_bit_cast(bf16x8, a), __builtin_bit_cast(bf16x8, b), c, 0, 0, 0);
}

// ---- swizzled byte offsets (XOR chunk-swizzle: 2-way bank aliasing = free) ----
__device__ __forceinline__ int swz128(int r, int kb) {   // 256B rows, 16 x 16B chunks
  return r * 256 + ((((kb >> 4) ^ (r & 15)) << 4) | (kb & 15));
}
__device__ __forceinline__ int swz32(int r, int db) {    // 64B rows, 4 x 16B chunks
  return r * 64 + ((((db >> 4) ^ ((r >> 1) & 3)) << 4) | (db & 15));
}
__device__ __forceinline__ int swz64(int r, int mb) {    // 128B rows, 8 x 16B chunks
  return r * 128 + ((((mb >> 4) ^ (r & 7)) << 4) | (mb & 15));
}

// LDS map (64 KB total):
//   [0,16384)      xs: x tile bf16 [64][128] swz128   (reused later as O tile "os")
//   [16384,49152)  qk[h]: h*8192 -> q [64][32] swz32 (+0), k [64][32] swz32 (+4096)
//                  (wave w's P tile [64][64] swz64 overlays qk[w] after S is done)
//   [49152,65536)  vT[h]: h*4096 -> V^T [32][64] bf16 swz64

__global__ __launch_bounds__(256, 2)
void win_attn_fused(const float* __restrict__ x,       // [B_,49,128]
                    const float* __restrict__ mask,    // [64,49,49]
                    const float* __restrict__ qkv_b,   // [384]
                    const float* __restrict__ proj_b,  // [128]
                    const unsigned short* __restrict__ wq_bf,  // [384][128] bf16
                    const unsigned short* __restrict__ wp_bf,  // [128][128] bf16
                    const float* __restrict__ bias_full,       // [4][49][49]
                    float* __restrict__ out) {         // [B_,49,128]
  __shared__ alignas(16) char smem[65536];
  const int tid = threadIdx.x;
  const int l  = tid & 63;
  const int w  = tid >> 6;
  const int lr = l & 15;
  const int lq = l >> 4;
  const int b  = blockIdx.x;
  const int wq = b & 63;              // mask index = b_ % nW

  // ---------------- Phase 0: stage x -> xs (bf16, swizzled) ----------------
  {
    const float* xw = x + (size_t)b * (49 * 128);
    #pragma unroll
    for (int i = 0; i < 4; ++i) {
      const int r = w * 4 + lq + i * 16;   // 0..63, each exactly once
      s16x8 v = {};
      if (r < 49) {
        const float4* p = reinterpret_cast<const float4*>(xw + r * 128 + lr * 8);
        float4 f0 = p[0], f1 = p[1];
        v[0] = (short)f2bf(f0.x); v[1] = (short)f2bf(f0.y);
        v[2] = (short)f2bf(f0.z); v[3] = (short)f2bf(f0.w);
        v[4] = (short)f2bf(f1.x); v[5] = (short)f2bf(f1.y);
        v[6] = (short)f2bf(f1.z); v[7] = (short)f2bf(f1.w);
      }
      *reinterpret_cast<s16x8*>(&smem[swz128(r, lr * 16)]) = v;
    }
  }
  __syncthreads();

  // ---------------- Phase 1: qkv = xs @ qkv_w^T + b ----------------
  // A-frags fully resident; wave w owns output cols [96w, 96w+96)
  s16x8 a1[4][4];
  #pragma unroll
  for (int mt = 0; mt < 4; ++mt)
    #pragma unroll
    for (int kt = 0; kt < 4; ++kt)
      a1[mt][kt] = *reinterpret_cast<const s16x8*>(
          &smem[swz128(mt * 16 + lr, kt * 64 + lq * 16)]);

  f32x4 acc[4][6];
  #pragma unroll
  for (int mt = 0; mt < 4; ++mt)
    #pragma unroll
    for (int nt = 0; nt < 6; ++nt)
      acc[mt][nt] = {};

  #pragma unroll
  for (int ntl = 0; ntl < 6; ++ntl) {
    const int o0 = (w * 6 + ntl) * 16;
    s16x8 bfr[4];
    #pragma unroll
    for (int kt = 0; kt < 4; ++kt)
      bfr[kt] = *reinterpret_cast<const s16x8*>(
          wq_bf + (o0 + lr) * 128 + kt * 32 + lq * 8);
    #pragma unroll
    for (int mt = 0; mt < 4; ++mt)
      #pragma unroll
      for (int kt = 0; kt < 4; ++kt)
        acc[mt][ntl] = MFMA(a1[mt][kt], bfr[kt], acc[mt][ntl]);
  }

  // scatter to q/k/vT (bf16) with bias (+scale for q)
  #pragma unroll
  for (int ntl = 0; ntl < 6; ++ntl) {
    const int o = (w * 6 + ntl) * 16 + lr;
    const float bo = qkv_b[o];
    const int sect = o >> 7;        // 0=q 1=k 2=v (uniform per frag)
    const int oo = o & 127;
    const int h2 = oo >> 5, d = oo & 31;
    #pragma unroll
    for (int mt = 0; mt < 4; ++mt) {
      #pragma unroll
      for (int j = 0; j < 4; ++j) {
        const int n = mt * 16 + lq * 4 + j;
        float val = acc[mt][ntl][j] + bo;
        int addr;
        if (sect == 0)      { val *= SCALE; addr = 16384 + h2 * 8192 + swz32(n, d * 2); }
        else if (sect == 1) { addr = 16384 + h2 * 8192 + 4096 + swz32(n, d * 2); }
        else                { addr = 49152 + h2 * 4096 + swz64(d, n * 2); }  // transposed
        *reinterpret_cast<unsigned short*>(&smem[addr]) = (unsigned short)f2bf(val);
      }
    }
  }
  __syncthreads();

  // ---------------- Phase 2: attention, wave w = head w ----------------
  const int qkb = 16384 + w * 8192;
  s16x8 qf[4], kf[4];
  #pragma unroll
  for (int t = 0; t < 4; ++t) {
    qf[t] = *reinterpret_cast<const s16x8*>(&smem[qkb + swz32(t * 16 + lr, lq * 16)]);
    kf[t] = *reinterpret_cast<const s16x8*>(&smem[qkb + 4096 + swz32(t * 16 + lr, lq * 16)]);
  }
  f32x4 sfr[4][4];
  #pragma unroll
  for (int mt = 0; mt < 4; ++mt)
    #pragma unroll
    for (int nt = 0; nt < 4; ++nt)
      sfr[mt][nt] = {};
  #pragma unroll
  for (int mt = 0; mt < 4; ++mt)
    #pragma unroll
    for (int nt = 0; nt < 4; ++nt)
      sfr[mt][nt] = MFMA(qf[mt], kf[nt], sfr[mt][nt]);  // K read A-style => B = K^T

  // + rel-pos bias + window mask; pad cols -> -1e30
  const float* bia = bias_full + w * 2401;
  const float* msk = mask + wq * 2401;
  #pragma unroll
  for (int nt = 0; nt < 4; ++nt) {
    const int m = nt * 16 + lr;
    #pragma unroll
    for (int mt = 0; mt < 4; ++mt)
      #pragma unroll
      for (int j = 0; j < 4; ++j) {
        const int n = mt * 16 + lq * 4 + j;
        if (m >= 49)       sfr[mt][nt][j] = -1e30f;
        else if (n < 49)   sfr[mt][nt][j] += bia[n * 49 + m] + msk[n * 49 + m];
      }
  }

  // row softmax: rows live across the 16-lane group (shfl_xor 1,2,4,8)
  #pragma unroll
  for (int mt = 0; mt < 4; ++mt) {
    #pragma unroll
    for (int j = 0; j < 4; ++j) {
      float mx = fmaxf(fmaxf(sfr[mt][0][j], sfr[mt][1][j]),
                       fmaxf(sfr[mt][2][j], sfr[mt][3][j]));
      #pragma unroll
      for (int off = 1; off < 16; off <<= 1) mx = fmaxf(mx, __shfl_xor(mx, off, 64));
      float sum = 0.f;
      #pragma unroll
      for (int nt = 0; nt < 4; ++nt) {
        float e = __expf(sfr[mt][nt][j] - mx);
        sfr[mt][nt][j] = e;
        sum += e;
      }
      #pragma unroll
      for (int off = 1; off < 16; off <<= 1) sum += __shfl_xor(sum, off, 64);
      const float rinv = 1.f / sum;
      #pragma unroll
      for (int nt = 0; nt < 4; ++nt) sfr[mt][nt][j] *= rinv;
    }
  }
  __syncthreads();

  // P (bf16) -> LDS, overlaying this head's dead q/k
  #pragma unroll
  for (int nt = 0; nt < 4; ++nt) {
    const int m = nt * 16 + lr;
    #pragma unroll
    for (int mt = 0; mt < 4; ++mt)
      #pragma unroll
      for (int j = 0; j < 4; ++j)
        *reinterpret_cast<unsigned short*>(
            &smem[qkb + swz64(mt * 16 + lq * 4 + j, m * 2)]) =
            (unsigned short)f2bf(sfr[mt][nt][j]);
  }
  __syncthreads();

  // PV: O[64][32] = P[64][64] @ V[64][32]
  s16x8 pf[4][2], vf[2][2];
  #pragma unroll
  for (int mt = 0; mt < 4; ++mt)
    #pragma unroll
    for (int kt = 0; kt < 2; ++kt)
      pf[mt][kt] = *reinterpret_cast<const s16x8*>(
          &smem[qkb + swz64(mt * 16 + lr, kt * 64 + lq * 16)]);
  #pragma unroll
  for (int nt = 0; nt < 2; ++nt)
    #pragma unroll
    for (int kt = 0; kt < 2; ++kt)
      vf[nt][kt] = *reinterpret_cast<const s16x8*>(
          &smem[49152 + w * 4096 + swz64(nt * 16 + lr, kt * 64 + lq * 16)]);
  f32x4 oacc[4][2];
  #pragma unroll
  for (int mt = 0; mt < 4; ++mt)
    #pragma unroll
    for (int nt = 0; nt < 2; ++nt)
      oacc[mt][nt] = {};
  #pragma unroll
  for (int mt = 0; mt < 4; ++mt)
    #pragma unroll
    for (int nt = 0; nt < 2; ++nt)
      #pragma unroll
      for (int kt = 0; kt < 2; ++kt)
        oacc[mt][nt] = MFMA(pf[mt][kt], vf[nt][kt], oacc[mt][nt]);

  // O -> os (reuses xs region; all xs reads completed before barrier #2)
  #pragma unroll
  for (int nt = 0; nt < 2; ++nt) {
    const int c = w * 32 + nt * 16 + lr;   // head-major channel
    #pragma unroll
    for (int mt = 0; mt < 4; ++mt)
      #pragma unroll
      for (int j = 0; j < 4; ++j)
        *reinterpret_cast<unsigned short*>(
            &smem[swz128(mt * 16 + lq * 4 + j, c * 2)]) =
            (unsigned short)f2bf(oacc[mt][nt][j]);
  }
  __syncthreads();

  // ---------------- Phase 3: proj + store ----------------
  s16x8 ap[4][4];
  #pragma unroll
  for (int mt = 0; mt < 4; ++mt)
    #pragma unroll
    for (int kt = 0; kt < 4; ++kt)
      ap[mt][kt] = *reinterpret_cast<const s16x8*>(
          &smem[swz128(mt * 16 + lr, kt * 64 + lq * 16)]);
  f32x4 pacc[4][2];
  #pragma unroll
  for (int mt = 0; mt < 4; ++mt)
    #pragma unroll
    for (int nt = 0; nt < 2; ++nt)
      pacc[mt][nt] = {};
  #pragma unroll
  for (int nt = 0; nt < 2; ++nt) {
    const int c = w * 32 + nt * 16 + lr;
    s16x8 bfr[4];
    #pragma unroll
    for (int kt = 0; kt < 4; ++kt)
      bfr[kt] = *reinterpret_cast<const s16x8*>(wp_bf + c * 128 + kt * 32 + lq * 8);
    #pragma unroll
    for (int mt = 0; mt < 4; ++mt)
      #pragma unroll
      for (int kt = 0; kt < 4; ++kt)
        pacc[mt][nt] = MFMA(ap[mt][kt], bfr[kt], pacc[mt][nt]);
  }
  float* ob = out + (size_t)b * (49 * 128);
  #pragma unroll
  for (int nt = 0; nt < 2; ++nt) {
    const int c = w * 32 + nt * 16 + lr;
    const float pb = proj_b[c];
    #pragma unroll
    for (int mt = 0; mt < 4; ++mt)
      #pragma unroll
      for (int j = 0; j < 4; ++j) {
        const int n = mt * 16 + lq * 4 + j;
        if (n < 49) ob[n * 128 + c] = pacc[mt][nt][j] + pb;
      }
  }
}

// ---- prep: weights -> bf16, bias gather (handles int32 OR int64 rel_index) ----
__global__ void prep_kernel(const float* __restrict__ qkv_w,
                            const float* __restrict__ proj_w,
                            const float* __restrict__ rpb,
                            const int* __restrict__ rel_raw,
                            unsigned short* __restrict__ wq_bf,
                            unsigned short* __restrict__ wp_bf,
                            float* __restrict__ bias_full) {
  const int i = blockIdx.x * 256 + threadIdx.x;
  if (i < 49152) {
    wq_bf[i] = (unsigned short)f2bf(qkv_w[i]);
  } else if (i < 65536) {
    wp_bf[i - 49152] = (unsigned short)f2bf(proj_w[i - 49152]);
  } else if (i < 65536 + 4 * 2401) {
    const int t = i - 65536;
    const int h = t / 2401, nm = t % 2401;
    // int64 buffers look like [v,0,v,0,...] in int32 view (values < 169)
    const bool is64 = (rel_raw[1] == 0) && (rel_raw[3] == 0) &&
                      (rel_raw[5] == 0) && (rel_raw[7] == 0);
    const int ridx = is64 ? rel_raw[2 * nm] : rel_raw[nm];
    bias_full[t] = rpb[ridx * 4 + h];   // bias[h][n][m] = rpb_table[idx][h]
  }
}

extern "C" void kernel_launch(void* const* d_in, const int* in_sizes, int n_in,
                              void* d_out, int out_size, void* d_ws, size_t ws_size,
                              hipStream_t stream) {
  const float* x      = (const float*)d_in[0];
  const float* mask   = (const float*)d_in[1];
  const float* qkv_w  = (const float*)d_in[2];
  const float* qkv_b  = (const float*)d_in[3];
  const float* proj_w = (const float*)d_in[4];
  const float* proj_b = (const float*)d_in[5];
  const float* rpb    = (const float*)d_in[6];
  const int*   rel    = (const int*)d_in[7];
  float* out = (float*)d_out;

  unsigned short* wq_bf = (unsigned short*)d_ws;                 // 98304 B
  unsigned short* wp_bf = wq_bf + 49152;                         // 32768 B
  float* bias_full = (float*)((char*)d_ws + 131072);             // 38416 B

  const int B_ = in_sizes[0] / (49 * 128);                       // 4096

  const int prep_n = 65536 + 4 * 2401;
  prep_kernel<<<(prep_n + 255) / 256, 256, 0, stream>>>(
      qkv_w, proj_w, rpb, rel, wq_bf, wp_bf, bias_full);
  win_attn_fused<<<B_, 256, 0, stream>>>(
      x, mask, qkv_b, proj_b, wq_bf, wp_bf, bias_full, out);
}

// Round 3
// 180.910 us; speedup vs baseline: 1.0645x; 1.0645x over previous
//
#include <hip/hip_runtime.h>
#include <stdint.h>

typedef __attribute__((ext_vector_type(4))) float f32x4;
typedef __attribute__((ext_vector_type(8))) short s16x8;
typedef __attribute__((ext_vector_type(8))) __bf16 bf16x8;
typedef __attribute__((ext_vector_type(2))) unsigned u32x2;

#define SCALE 0.17677669529663687f  // 32^-0.5

__device__ __forceinline__ unsigned f2bf(float f) {
  unsigned u = __builtin_bit_cast(unsigned, f);
  u += 0x7fffu + ((u >> 16) & 1u);   // RNE
  return u >> 16;
}
__device__ __forceinline__ unsigned pk2(float lo, float hi) {
  return f2bf(lo) | (f2bf(hi) << 16);
}
__device__ __forceinline__ unsigned short cv1(float v) {
  return (unsigned short)f2bf(v);
}

__device__ __forceinline__ f32x4 MFMA(s16x8 a, s16x8 b, f32x4 c) {
  return __builtin_amdgcn_mfma_f32_16x16x32_bf16(
      __builtin_bit_cast(bf16x8, a), __builtin_bit_cast(bf16x8, b), c, 0, 0, 0);
}

// ---- XOR chunk swizzles (16B chunks), consistent on write & read ----
__device__ __forceinline__ int swzq(int n, int db) {   // 64B rows (q/k [64][32]bf16)
  return n * 64 + ((((db >> 4) ^ ((n >> 1) & 3)) << 4) | (db & 15));
}
__device__ __forceinline__ int swz64(int r, int cb) {  // 128B rows ([*][64]bf16)
  return r * 128 + ((((cb >> 4) ^ (r & 7)) << 4) | (cb & 15));
}
__device__ __forceinline__ int swzos(int n, int cb) {  // 256B rows (Os [64][128]bf16)
  return n * 256 + ((((cb >> 4) ^ (n & 15)) << 4) | (cb & 15));
}

// LDS map (48 KB):
//  region A [0,32768): head h at h*8192: q[64][32] (+0, swzq), k[64][32] (+4096, swzq)
//                      Pn[64][64] (swz64) overlays q+k of own head (wave-local)
//  region B [32768,49152): vT[h]: 32768+h*4096: [32][64] swz64
//                      Os[64][128] (swzos) overlays all vT after barrier
template <int PADDED>
__global__ __launch_bounds__(256, 3)
void win_attn(const float* __restrict__ x,        // [B_,49,128]
              const float* __restrict__ mask,     // [64,49,49]
              const float* __restrict__ qkv_bs,   // [384] (q part pre-scaled)
              const float* __restrict__ proj_b,   // [128]
              const unsigned short* __restrict__ wq_bf,  // [384][128] bf16 (q rows pre-scaled)
              const unsigned short* __restrict__ wp_bf,  // [128][128] bf16
              const float* __restrict__ bias_full,       // [4][49][49]
              const float* __restrict__ bias_pad,        // [4][64][64]
              const float* __restrict__ mask_pad,        // [64][64][64]
              float* __restrict__ out) {          // [B_,49,128]
  __shared__ alignas(16) char smem[49152];
  const int tid = threadIdx.x;
  const int l = tid & 63, w = tid >> 6;
  const int lr = l & 15, lq = l >> 4;
  const int b = blockIdx.x;
  const int wq = b & 63;

  // ---- x fragments: global -> reg (bf16), rows clamped to 48 (pad-safe) ----
  s16x8 a1[4][4];
  {
    const float* xw = x + (size_t)b * (49 * 128);
    #pragma unroll
    for (int nt = 0; nt < 4; ++nt) {
      const int rowc = min(16 * nt + lr, 48);
      #pragma unroll
      for (int kt = 0; kt < 4; ++kt) {
        const float4* p = reinterpret_cast<const float4*>(xw + rowc * 128 + kt * 32 + lq * 8);
        float4 f0 = p[0], f1 = p[1];
        union { unsigned u[4]; s16x8 v; } U;
        U.u[0] = pk2(f0.x, f0.y); U.u[1] = pk2(f0.z, f0.w);
        U.u[2] = pk2(f1.x, f1.y); U.u[3] = pk2(f1.z, f1.w);
        a1[nt][kt] = U.v;
      }
    }
  }

  // ---- D1 = W_qk · x^T  (rows o in j-dim -> b64 scatter to q[n][d], k[n][d]) ----
  #pragma unroll
  for (int f = 0; f < 4; ++f) {
    const int sect = f >> 1;                       // 0=q 1=k
    const int obase = sect * 128 + 32 * w + 16 * (f & 1);
    s16x8 wf[4];
    #pragma unroll
    for (int kt = 0; kt < 4; ++kt)
      wf[kt] = *reinterpret_cast<const s16x8*>(wq_bf + (obase + lr) * 128 + kt * 32 + lq * 8);
    const f32x4 bia4 = *reinterpret_cast<const f32x4*>(qkv_bs + obase + 4 * lq);
    const int base = w * 8192 + sect * 4096;
    const int db = 32 * (f & 1) + 8 * lq;          // d0*2 bytes
    #pragma unroll
    for (int nt = 0; nt < 4; ++nt) {
      f32x4 acc = {};
      #pragma unroll
      for (int kt = 0; kt < 4; ++kt) acc = MFMA(wf[kt], a1[nt][kt], acc);
      acc += bia4;
      u32x2 pkv; pkv[0] = pk2(acc[0], acc[1]); pkv[1] = pk2(acc[2], acc[3]);
      *reinterpret_cast<u32x2*>(&smem[base + swzq(16 * nt + lr, db)]) = pkv;
    }
  }
  // ---- D2 = x · W_v^T  (cols d in lr -> b64 scatter to vT[d][n]) ----
  #pragma unroll
  for (int vt = 0; vt < 2; ++vt) {
    const int obase = 256 + 32 * w + 16 * vt;
    s16x8 wf[4];
    #pragma unroll
    for (int kt = 0; kt < 4; ++kt)
      wf[kt] = *reinterpret_cast<const s16x8*>(wq_bf + (obase + lr) * 128 + kt * 32 + lq * 8);
    const float bo = qkv_bs[obase + lr];
    const int d = 16 * vt + lr;
    #pragma unroll
    for (int nt = 0; nt < 4; ++nt) {
      f32x4 acc = {};
      #pragma unroll
      for (int kt = 0; kt < 4; ++kt) acc = MFMA(a1[nt][kt], wf[kt], acc);
      acc += bo;
      u32x2 pkv; pkv[0] = pk2(acc[0], acc[1]); pkv[1] = pk2(acc[2], acc[3]);
      *reinterpret_cast<u32x2*>(&smem[32768 + w * 4096 + swz64(d, (16 * nt + 4 * lq) * 2)]) = pkv;
    }
  }
  asm volatile("" ::: "memory");   // wave-local: order scatter before frag reads

  // ---- S^T = K · Q^T  (head w, wave-local) ----
  const int qb = w * 8192, kb = w * 8192 + 4096;
  s16x8 qf[4], kf[4];
  #pragma unroll
  for (int t = 0; t < 4; ++t) {
    qf[t] = *reinterpret_cast<const s16x8*>(&smem[qb + swzq(16 * t + lr, 16 * lq)]);
    kf[t] = *reinterpret_cast<const s16x8*>(&smem[kb + swzq(16 * t + lr, 16 * lq)]);
  }
  f32x4 sfr[4][4];   // [mtm][ntn], row m=16mtm+4lq+j, col n=16ntn+lr
  #pragma unroll
  for (int mtm = 0; mtm < 4; ++mtm)
    #pragma unroll
    for (int ntn = 0; ntn < 4; ++ntn)
      sfr[mtm][ntn] = MFMA(kf[mtm], qf[ntn], f32x4{});

  // ---- + rel-pos bias + window mask ----
  if (PADDED) {
    #pragma unroll
    for (int mtm = 0; mtm < 4; ++mtm)
      #pragma unroll
      for (int ntn = 0; ntn < 4; ++ntn) {
        const int n = 16 * ntn + lr, m0 = 16 * mtm + 4 * lq;
        f32x4 bb = *reinterpret_cast<const f32x4*>(bias_pad + (w * 64 + n) * 64 + m0);
        f32x4 mm = *reinterpret_cast<const f32x4*>(mask_pad + (wq * 64 + n) * 64 + m0);
        sfr[mtm][ntn] += bb + mm;
      }
  } else {
    #pragma unroll
    for (int mtm = 0; mtm < 4; ++mtm)
      #pragma unroll
      for (int ntn = 0; ntn < 4; ++ntn) {
        const int n = 16 * ntn + lr;
        #pragma unroll
        for (int j = 0; j < 4; ++j) {
          const int m = 16 * mtm + 4 * lq + j;
          if (m < 49 && n < 49)
            sfr[mtm][ntn][j] += bias_full[w * 2401 + n * 49 + m] + mask[wq * 2401 + n * 49 + m];
        }
      }
  }
  // mask pad rows m>=49 (only mtm==3 can exceed; m=48+4lq+j)
  #pragma unroll
  for (int ntn = 0; ntn < 4; ++ntn) {
    f32x4 v = sfr[3][ntn];
    v[0] = (lq == 0) ? v[0] : -1e30f;
    v[1] = -1e30f; v[2] = -1e30f; v[3] = -1e30f;
    sfr[3][ntn] = v;
  }

  // ---- softmax over m (16 in-lane + shfl_xor 16,32); defer 1/sum to O-scale ----
  float rinv[4];
  asm volatile("" ::: "memory");   // q/k regs consumed; Pn will overlay q/k
  #pragma unroll
  for (int ntn = 0; ntn < 4; ++ntn) {
    float mx = -1e30f;
    #pragma unroll
    for (int mtm = 0; mtm < 4; ++mtm)
      #pragma unroll
      for (int j = 0; j < 4; ++j) mx = fmaxf(mx, sfr[mtm][ntn][j]);
    mx = fmaxf(mx, __shfl_xor(mx, 16, 64));
    mx = fmaxf(mx, __shfl_xor(mx, 32, 64));
    float s = 0.f;
    #pragma unroll
    for (int mtm = 0; mtm < 4; ++mtm) {
      f32x4 v = sfr[mtm][ntn];
      #pragma unroll
      for (int j = 0; j < 4; ++j) { v[j] = __expf(v[j] - mx); s += v[j]; }
      sfr[mtm][ntn] = v;
    }
    s += __shfl_xor(s, 16, 64);
    s += __shfl_xor(s, 32, 64);
    rinv[ntn] = 1.f / s;
    // P (unnormalized, <=1) -> Pn[n][m] b64 packed, overlays own head's q/k
    const int n = 16 * ntn + lr;
    #pragma unroll
    for (int mtm = 0; mtm < 4; ++mtm) {
      u32x2 pkv;
      pkv[0] = pk2(sfr[mtm][ntn][0], sfr[mtm][ntn][1]);
      pkv[1] = pk2(sfr[mtm][ntn][2], sfr[mtm][ntn][3]);
      *reinterpret_cast<u32x2*>(&smem[qb + swz64(n, (16 * mtm + 4 * lq) * 2)]) = pkv;
    }
  }
  asm volatile("" ::: "memory");

  // ---- O^T = V^T · P^T : A = vT rows d, B~ = Pn rows n (both b128) ----
  s16x8 vf[2][2], pf2[4][2];
  #pragma unroll
  for (int dt = 0; dt < 2; ++dt)
    #pragma unroll
    for (int kt = 0; kt < 2; ++kt)
      vf[dt][kt] = *reinterpret_cast<const s16x8*>(
          &smem[32768 + w * 4096 + swz64(16 * dt + lr, 64 * kt + 16 * lq)]);
  #pragma unroll
  for (int ntn = 0; ntn < 4; ++ntn)
    #pragma unroll
    for (int kt = 0; kt < 2; ++kt)
      pf2[ntn][kt] = *reinterpret_cast<const s16x8*>(
          &smem[qb + swz64(16 * ntn + lr, 64 * kt + 16 * lq)]);
  f32x4 ot[2][4];
  #pragma unroll
  for (int dt = 0; dt < 2; ++dt)
    #pragma unroll
    for (int ntn = 0; ntn < 4; ++ntn) {
      f32x4 acc = {};
      #pragma unroll
      for (int kt = 0; kt < 2; ++kt) acc = MFMA(vf[dt][kt], pf2[ntn][kt], acc);
      ot[dt][ntn] = acc * rinv[ntn];
    }

  __syncthreads();   // all waves done reading vT before Os overlays region B

  // ---- Os[n][c] scatter (b64): O^T frag rows d=c' in j-dim ----
  #pragma unroll
  for (int dt = 0; dt < 2; ++dt)
    #pragma unroll
    for (int ntn = 0; ntn < 4; ++ntn) {
      const int n = 16 * ntn + lr;
      const int c0 = 32 * w + 16 * dt + 4 * lq;
      u32x2 pkv;
      pkv[0] = pk2(ot[dt][ntn][0], ot[dt][ntn][1]);
      pkv[1] = pk2(ot[dt][ntn][2], ot[dt][ntn][3]);
      *reinterpret_cast<u32x2*>(&smem[32768 + swzos(n, 2 * c0)]) = pkv;
    }
  __syncthreads();

  // ---- proj^T = Wp · O^T : A = Wp rows c, B~ = Os rows n; float4 stores ----
  s16x8 wpf[2][4], osf[4][4];
  #pragma unroll
  for (int ct = 0; ct < 2; ++ct)
    #pragma unroll
    for (int kt = 0; kt < 4; ++kt)
      wpf[ct][kt] = *reinterpret_cast<const s16x8*>(
          wp_bf + (32 * w + 16 * ct + lr) * 128 + kt * 32 + lq * 8);
  #pragma unroll
  for (int nt = 0; nt < 4; ++nt)
    #pragma unroll
    for (int kt = 0; kt < 4; ++kt)
      osf[nt][kt] = *reinterpret_cast<const s16x8*>(
          &smem[32768 + swzos(16 * nt + lr, (32 * kt + 8 * lq) * 2)]);
  float* ob = out + (size_t)b * (49 * 128);
  #pragma unroll
  for (int ct = 0; ct < 2; ++ct) {
    const int c0 = 32 * w + 16 * ct + 4 * lq;
    const f32x4 pb4 = *reinterpret_cast<const f32x4*>(proj_b + c0);
    #pragma unroll
    for (int nt = 0; nt < 4; ++nt) {
      f32x4 acc = {};
      #pragma unroll
      for (int kt = 0; kt < 4; ++kt) acc = MFMA(wpf[ct][kt], osf[nt][kt], acc);
      acc += pb4;
      const int n = 16 * nt + lr;
      if (n < 49) *reinterpret_cast<f32x4*>(ob + n * 128 + c0) = acc;
    }
  }
}

// ---- prep: bf16 weights (q pre-scaled), scaled qkv_b, bias tables ----
__global__ void prep_kernel(const float* __restrict__ qkv_w,
                            const float* __restrict__ qkv_b,
                            const float* __restrict__ proj_w,
                            const float* __restrict__ rpb,
                            const int* __restrict__ rel_raw,
                            const float* __restrict__ mask,
                            unsigned short* __restrict__ wq_bf,
                            unsigned short* __restrict__ wp_bf,
                            float* __restrict__ qkv_bs,
                            float* __restrict__ bias_full,
                            float* __restrict__ bias_pad,
                            float* __restrict__ mask_pad,
                            int padded) {
  const int i = blockIdx.x * 256 + threadIdx.x;
  if (i < 49152) {
    float v = qkv_w[i];
    if (i < 16384) v *= SCALE;                    // q rows (o<128)
    wq_bf[i] = cv1(v);
  } else if (i < 65536) {
    wp_bf[i - 49152] = cv1(proj_w[i - 49152]);
  } else if (i < 65920) {
    const int t = i - 65536;
    float v = qkv_b[t];
    if (t < 128) v *= SCALE;
    qkv_bs[t] = v;
  } else if (i < 75524) {
    const int t = i - 65920;                      // 4*2401
    const int h = t / 2401, nm = t % 2401;
    const bool is64 = (rel_raw[1] == 0) && (rel_raw[3] == 0) &&
                      (rel_raw[5] == 0) && (rel_raw[7] == 0);
    const int ridx = is64 ? rel_raw[2 * nm] : rel_raw[nm];
    bias_full[t] = rpb[ridx * 4 + h];
  } else if (padded && i < 75524 + 16384) {
    const int j = i - 75524;                      // bias_pad [4][64][64]
    const int h = j >> 12, r = (j >> 6) & 63, m = j & 63;
    float v = 0.f;
    if (r < 49 && m < 49) {
      const bool is64 = (rel_raw[1] == 0) && (rel_raw[3] == 0) &&
                        (rel_raw[5] == 0) && (rel_raw[7] == 0);
      const int nm = r * 49 + m;
      const int ridx = is64 ? rel_raw[2 * nm] : rel_raw[nm];
      v = rpb[ridx * 4 + h];
    }
    bias_pad[j] = v;
  } else if (padded && i < 75524 + 16384 + 262144) {
    const int t = i - 75524 - 16384;              // mask_pad [64][64][64]
    const int wqi = t >> 12, n = (t >> 6) & 63, m = t & 63;
    mask_pad[t] = (n < 49 && m < 49) ? mask[wqi * 2401 + n * 49 + m] : 0.f;
  }
}

extern "C" void kernel_launch(void* const* d_in, const int* in_sizes, int n_in,
                              void* d_out, int out_size, void* d_ws, size_t ws_size,
                              hipStream_t stream) {
  const float* x      = (const float*)d_in[0];
  const float* mask   = (const float*)d_in[1];
  const float* qkv_w  = (const float*)d_in[2];
  const float* qkv_b  = (const float*)d_in[3];
  const float* proj_w = (const float*)d_in[4];
  const float* proj_b = (const float*)d_in[5];
  const float* rpb    = (const float*)d_in[6];
  const int*   rel    = (const int*)d_in[7];
  float* out = (float*)d_out;

  char* ws = (char*)d_ws;
  unsigned short* wq_bf = (unsigned short*)(ws + 0);         // 98304
  unsigned short* wp_bf = (unsigned short*)(ws + 98304);     // 32768
  float* qkv_bs    = (float*)(ws + 131072);                  // 1536
  float* bias_full = (float*)(ws + 132608);                  // 38416
  float* bias_pad  = (float*)(ws + 171024);                  // 65536
  float* mask_pad  = (float*)(ws + 236560);                  // 1048576 -> end 1285136

  const int padded = (ws_size >= 1285136) ? 1 : 0;
  const int B_ = in_sizes[0] / (49 * 128);

  const int prep_n = 75524 + (padded ? (16384 + 262144) : 0);
  prep_kernel<<<(prep_n + 255) / 256, 256, 0, stream>>>(
      qkv_w, qkv_b, proj_w, rpb, rel, mask,
      wq_bf, wp_bf, qkv_bs, bias_full, bias_pad, mask_pad, padded);
  if (padded)
    win_attn<1><<<B_, 256, 0, stream>>>(x, mask, qkv_bs, proj_b, wq_bf, wp_bf,
                                        bias_full, bias_pad, mask_pad, out);
  else
    win_attn<0><<<B_, 256, 0, stream>>>(x, mask, qkv_bs, proj_b, wq_bf, wp_bf,
                                        bias_full, bias_pad, mask_pad, out);
}

// Round 4
// 151.285 us; speedup vs baseline: 1.2729x; 1.1958x over previous
//
#include <hip/hip_runtime.h>
#include <stdint.h>

typedef __attribute__((ext_vector_type(4))) float f32x4;
typedef __attribute__((ext_vector_type(8))) short s16x8;
typedef __attribute__((ext_vector_type(4))) short s16x4;
typedef __attribute__((ext_vector_type(8))) __bf16 bf16x8;
typedef __attribute__((ext_vector_type(2))) unsigned u32x2;

#define SCALE 0.17677669529663687f  // 32^-0.5

__device__ __forceinline__ unsigned f2bf(float f) {
  unsigned u = __builtin_bit_cast(unsigned, f);
  u += 0x7fffu + ((u >> 16) & 1u);   // RNE
  return u >> 16;
}
__device__ __forceinline__ unsigned pk2(float lo, float hi) {
  return f2bf(lo) | (f2bf(hi) << 16);
}
__device__ __forceinline__ unsigned short cv1(float v) {
  return (unsigned short)f2bf(v);
}

__device__ __forceinline__ f32x4 MFMA(s16x8 a, s16x8 b, f32x4 c) {  // K=32
  return __builtin_amdgcn_mfma_f32_16x16x32_bf16(
      __builtin_bit_cast(bf16x8, a), __builtin_bit_cast(bf16x8, b), c, 0, 0, 0);
}
__device__ __forceinline__ f32x4 MFMA16(u32x2 a, u32x2 b, f32x4 c) {  // K=16
#if __has_builtin(__builtin_amdgcn_mfma_f32_16x16x16bf16_1k)
  return __builtin_amdgcn_mfma_f32_16x16x16bf16_1k(
      __builtin_bit_cast(s16x4, a), __builtin_bit_cast(s16x4, b), c, 0, 0, 0);
#else
  f32x4 d;
  asm("v_mfma_f32_16x16x16_bf16 %0, %1, %2, %3"
      : "=v"(d) : "v"(a), "v"(b), "v"(c));
  return d;
#endif
}

// LDS (16 KB): xs [64][256B] bf16 XOR-chunk-swizzled; Os overlays after phase 1.
// addr(r, chunk) = r*256 + ((chunk ^ (r&15)) & 15)*16   (16B chunks, 2-way max)

template <int PADDED>
__global__ __launch_bounds__(256, 4)
void win_attn(const float* __restrict__ x,        // [B_,49,128]
              const float* __restrict__ mask,     // [64,49,49]
              const float* __restrict__ qkv_bs,   // [384] (q part pre-scaled)
              const float* __restrict__ proj_b,   // [128]
              const unsigned short* __restrict__ wq_bf,  // [384][128] bf16 (q pre-scaled)
              const unsigned short* __restrict__ wp_bf,  // [128][128] bf16
              const float* __restrict__ bias_full,       // [4][49][49]
              const float* __restrict__ bias_pad,        // [4][64][64]
              const float* __restrict__ mask_pad,        // [64][64][64]
              float* __restrict__ out) {          // [B_,49,128]
  __shared__ alignas(16) char smem[16384];
  const int tid = threadIdx.x;
  const int l = tid & 63, w = tid >> 6;
  const int lr = l & 15, lq = l >> 4;
  const int b = blockIdx.x;
  const int wq = b & 63;

  // ---------------- Phase 0: stage x -> xs (bf16, swizzled), cvt once ----------------
  {
    const float* xw = x + (size_t)b * (49 * 128);
    #pragma unroll
    for (int i = 0; i < 4; ++i) {
      const int r = w * 4 + lq + i * 16;   // 0..63 exactly once per thread-tuple
      s16x8 v = {};
      if (r < 49) {
        const float4* p = reinterpret_cast<const float4*>(xw + r * 128 + lr * 8);
        float4 f0 = p[0], f1 = p[1];
        union { unsigned u[4]; s16x8 v8; } U;
        U.u[0] = pk2(f0.x, f0.y); U.u[1] = pk2(f0.z, f0.w);
        U.u[2] = pk2(f1.x, f1.y); U.u[3] = pk2(f1.z, f1.w);
        v = U.v8;
      }
      *reinterpret_cast<s16x8*>(&smem[r * 256 + (((lr ^ (r & 15)) & 15) << 4)]) = v;
    }
  }
  __syncthreads();

  // precomputed a1-row ds addresses (row 16nt+lr, chunk 4kt+lq)
  int addrA[4][4];
  #pragma unroll
  for (int nt = 0; nt < 4; ++nt)
    #pragma unroll
    for (int kt = 0; kt < 4; ++kt)
      addrA[nt][kt] = (16 * nt + lr) * 256 + ((((4 * kt + lq) ^ lr) & 15) << 4);

  // ---------------- Phase 1: qkv, outputs land directly as K=16 frags ----------------
  u32x2 qB[4][2], kB[4][2], vA[2][4];   // q/k: [n-tile][d-half]; v: [d-half][m-tile]
  #pragma unroll
  for (int g = 0; g < 6; ++g) {
    const int sect = g >> 1;            // 0=q 1=k 2=v
    const int half = g & 1;
    const int obase = sect * 128 + 32 * w + 16 * half;
    s16x8 wf[4];
    #pragma unroll
    for (int kt = 0; kt < 4; ++kt)
      wf[kt] = *reinterpret_cast<const s16x8*>(wq_bf + (obase + lr) * 128 + kt * 32 + lq * 8);
    if (sect < 2) {
      // D = W · x^T : rows o=4lq+j, cols n=lr  ->  B-frag (n=lr, d=4lq+j)
      const f32x4 bia4 = *reinterpret_cast<const f32x4*>(qkv_bs + obase + 4 * lq);
      #pragma unroll
      for (int nt = 0; nt < 4; ++nt) {
        s16x8 ar[4];
        #pragma unroll
        for (int kt = 0; kt < 4; ++kt)
          ar[kt] = *reinterpret_cast<const s16x8*>(&smem[addrA[nt][kt]]);
        f32x4 acc = {};
        #pragma unroll
        for (int kt = 0; kt < 4; ++kt) acc = MFMA(wf[kt], ar[kt], acc);
        acc += bia4;
        u32x2 fr; fr[0] = pk2(acc[0], acc[1]); fr[1] = pk2(acc[2], acc[3]);
        if (sect == 0) qB[nt][half] = fr; else kB[nt][half] = fr;
      }
    } else {
      // D = x · W_v^T : rows m=4lq+j, cols d=lr  ->  A-frag (d=lr, m=4lq+j)
      const float bo = qkv_bs[obase + lr];
      #pragma unroll
      for (int mt = 0; mt < 4; ++mt) {
        s16x8 ar[4];
        #pragma unroll
        for (int kt = 0; kt < 4; ++kt)
          ar[kt] = *reinterpret_cast<const s16x8*>(&smem[addrA[mt][kt]]);
        f32x4 acc = {};
        #pragma unroll
        for (int kt = 0; kt < 4; ++kt) acc = MFMA(ar[kt], wf[kt], acc);
        acc += bo;
        u32x2 fr; fr[0] = pk2(acc[0], acc[1]); fr[1] = pk2(acc[2], acc[3]);
        vA[half][mt] = fr;
      }
    }
  }
  __syncthreads();   // xs fully consumed; Os may overlay

  // ---------------- Phase 2: attention, fully in registers (wave = head) ----------------
  const float* biaW = bias_pad + w * 4096;
  const float* mskW = mask_pad + wq * 4096;
  #pragma unroll
  for (int ntn = 0; ntn < 4; ++ntn) {
    const int n = 16 * ntn + lr;
    f32x4 sacc[4];   // S^T tile column: row m=16mtm+4lq+j, col n
    #pragma unroll
    for (int mtm = 0; mtm < 4; ++mtm) {
      sacc[mtm] = MFMA16(kB[mtm][0], qB[ntn][0], f32x4{});
      sacc[mtm] = MFMA16(kB[mtm][1], qB[ntn][1], sacc[mtm]);
    }
    if (PADDED) {
      #pragma unroll
      for (int mtm = 0; mtm < 4; ++mtm) {
        const int m0 = 16 * mtm + 4 * lq;
        f32x4 bb = *reinterpret_cast<const f32x4*>(biaW + n * 64 + m0);
        f32x4 mm = *reinterpret_cast<const f32x4*>(mskW + n * 64 + m0);
        sacc[mtm] += bb + mm;
      }
    } else {
      #pragma unroll
      for (int mtm = 0; mtm < 4; ++mtm)
        #pragma unroll
        for (int j = 0; j < 4; ++j) {
          const int m = 16 * mtm + 4 * lq + j;
          if (m < 49 && n < 49)
            sacc[mtm][j] += bias_full[w * 2401 + n * 49 + m] + mask[wq * 2401 + n * 49 + m];
        }
    }
    // mask pad rows m>=49 (mtm==3: m=48+4lq+j)
    {
      f32x4 v = sacc[3];
      v[0] = (lq == 0) ? v[0] : -1e30f;
      v[1] = -1e30f; v[2] = -1e30f; v[3] = -1e30f;
      sacc[3] = v;
    }
    // softmax over m (16 in-lane + shfl_xor 16,32); 1/sum deferred to O-scale
    float mx = -1e30f;
    #pragma unroll
    for (int mtm = 0; mtm < 4; ++mtm)
      #pragma unroll
      for (int j = 0; j < 4; ++j) mx = fmaxf(mx, sacc[mtm][j]);
    mx = fmaxf(mx, __shfl_xor(mx, 16, 64));
    mx = fmaxf(mx, __shfl_xor(mx, 32, 64));
    float s = 0.f;
    #pragma unroll
    for (int mtm = 0; mtm < 4; ++mtm) {
      f32x4 v = sacc[mtm];
      #pragma unroll
      for (int j = 0; j < 4; ++j) { v[j] = __expf(v[j] - mx); s += v[j]; }
      sacc[mtm] = v;
    }
    s += __shfl_xor(s, 16, 64);
    s += __shfl_xor(s, 32, 64);
    const float ri = 1.f / s;
    // P^T frags (m=4lq+j in elem, n=lr) — direct PV B-operand
    u32x2 p[4];
    #pragma unroll
    for (int mtm = 0; mtm < 4; ++mtm) {
      p[mtm][0] = pk2(sacc[mtm][0], sacc[mtm][1]);
      p[mtm][1] = pk2(sacc[mtm][2], sacc[mtm][3]);
    }
    // O^T column: rows d (=4lq+j), col n; scale by 1/sum; b64 to Os
    #pragma unroll
    for (int dt = 0; dt < 2; ++dt) {
      f32x4 oc = {};
      #pragma unroll
      for (int mtm = 0; mtm < 4; ++mtm) oc = MFMA16(vA[dt][mtm], p[mtm], oc);
      oc *= ri;
      u32x2 ov; ov[0] = pk2(oc[0], oc[1]); ov[1] = pk2(oc[2], oc[3]);
      const int cb = 64 * w + 32 * dt + 8 * lq;   // byte col = 2*(32w+16dt+4lq)
      *reinterpret_cast<u32x2*>(
          &smem[n * 256 + (((((cb >> 4) ^ lr) & 15) << 4) | (cb & 15))]) = ov;
    }
  }
  __syncthreads();

  // ---------------- Phase 3: proj^T = Wp · Os^T + b; coalesced f32x4 stores ----------------
  s16x8 wpf[2][4];
  #pragma unroll
  for (int ct = 0; ct < 2; ++ct)
    #pragma unroll
    for (int kt = 0; kt < 4; ++kt)
      wpf[ct][kt] = *reinterpret_cast<const s16x8*>(
          wp_bf + (32 * w + 16 * ct + lr) * 128 + kt * 32 + lq * 8);
  float* ob = out + (size_t)b * (49 * 128);
  #pragma unroll
  for (int nt = 0; nt < 4; ++nt) {
    const int n = 16 * nt + lr;
    s16x8 osf[4];
    #pragma unroll
    for (int kt = 0; kt < 4; ++kt) {
      const int cb = 64 * kt + 16 * lq;
      osf[kt] = *reinterpret_cast<const s16x8*>(
          &smem[n * 256 + (((((cb >> 4) ^ lr) & 15) << 4) | (cb & 15))]);
    }
    #pragma unroll
    for (int ct = 0; ct < 2; ++ct) {
      const int c0 = 32 * w + 16 * ct + 4 * lq;
      f32x4 acc = {};
      #pragma unroll
      for (int kt = 0; kt < 4; ++kt) acc = MFMA(wpf[ct][kt], osf[kt], acc);
      acc += *reinterpret_cast<const f32x4*>(proj_b + c0);
      if (n < 49) *reinterpret_cast<f32x4*>(ob + n * 128 + c0) = acc;
    }
  }
}

// ---- prep: bf16 weights (q pre-scaled), scaled qkv_b, bias tables ----
__global__ void prep_kernel(const float* __restrict__ qkv_w,
                            const float* __restrict__ qkv_b,
                            const float* __restrict__ proj_w,
                            const float* __restrict__ rpb,
                            const int* __restrict__ rel_raw,
                            const float* __restrict__ mask,
                            unsigned short* __restrict__ wq_bf,
                            unsigned short* __restrict__ wp_bf,
                            float* __restrict__ qkv_bs,
                            float* __restrict__ bias_full,
                            float* __restrict__ bias_pad,
                            float* __restrict__ mask_pad,
                            int padded) {
  const int i = blockIdx.x * 256 + threadIdx.x;
  if (i < 49152) {
    float v = qkv_w[i];
    if (i < 16384) v *= SCALE;                    // q rows (o<128)
    wq_bf[i] = cv1(v);
  } else if (i < 65536) {
    wp_bf[i - 49152] = cv1(proj_w[i - 49152]);
  } else if (i < 65920) {
    const int t = i - 65536;
    float v = qkv_b[t];
    if (t < 128) v *= SCALE;
    qkv_bs[t] = v;
  } else if (i < 75524) {
    const int t = i - 65920;                      // 4*2401
    const int h = t / 2401, nm = t % 2401;
    const bool is64 = (rel_raw[1] == 0) && (rel_raw[3] == 0) &&
                      (rel_raw[5] == 0) && (rel_raw[7] == 0);
    const int ridx = is64 ? rel_raw[2 * nm] : rel_raw[nm];
    bias_full[t] = rpb[ridx * 4 + h];
  } else if (padded && i < 75524 + 16384) {
    const int j = i - 75524;                      // bias_pad [4][64][64]
    const int h = j >> 12, r = (j >> 6) & 63, m = j & 63;
    float v = 0.f;
    if (r < 49 && m < 49) {
      const bool is64 = (rel_raw[1] == 0) && (rel_raw[3] == 0) &&
                        (rel_raw[5] == 0) && (rel_raw[7] == 0);
      const int nm = r * 49 + m;
      const int ridx = is64 ? rel_raw[2 * nm] : rel_raw[nm];
      v = rpb[ridx * 4 + h];
    }
    bias_pad[j] = v;
  } else if (padded && i < 75524 + 16384 + 262144) {
    const int t = i - 75524 - 16384;              // mask_pad [64][64][64]
    const int wqi = t >> 12, n = (t >> 6) & 63, m = t & 63;
    mask_pad[t] = (n < 49 && m < 49) ? mask[wqi * 2401 + n * 49 + m] : 0.f;
  }
}

extern "C" void kernel_launch(void* const* d_in, const int* in_sizes, int n_in,
                              void* d_out, int out_size, void* d_ws, size_t ws_size,
                              hipStream_t stream) {
  const float* x      = (const float*)d_in[0];
  const float* mask   = (const float*)d_in[1];
  const float* qkv_w  = (const float*)d_in[2];
  const float* qkv_b  = (const float*)d_in[3];
  const float* proj_w = (const float*)d_in[4];
  const float* proj_b = (const float*)d_in[5];
  const float* rpb    = (const float*)d_in[6];
  const int*   rel    = (const int*)d_in[7];
  float* out = (float*)d_out;

  char* ws = (char*)d_ws;
  unsigned short* wq_bf = (unsigned short*)(ws + 0);         // 98304
  unsigned short* wp_bf = (unsigned short*)(ws + 98304);     // 32768
  float* qkv_bs    = (float*)(ws + 131072);                  // 1536
  float* bias_full = (float*)(ws + 132608);                  // 38416
  float* bias_pad  = (float*)(ws + 171024);                  // 65536
  float* mask_pad  = (float*)(ws + 236560);                  // 1048576 -> end 1285136

  const int padded = (ws_size >= 1285136) ? 1 : 0;
  const int B_ = in_sizes[0] / (49 * 128);

  const int prep_n = 75524 + (padded ? (16384 + 262144) : 0);
  prep_kernel<<<(prep_n + 255) / 256, 256, 0, stream>>>(
      qkv_w, qkv_b, proj_w, rpb, rel, mask,
      wq_bf, wp_bf, qkv_bs, bias_full, bias_pad, mask_pad, padded);
  if (padded)
    win_attn<1><<<B_, 256, 0, stream>>>(x, mask, qkv_bs, proj_b, wq_bf, wp_bf,
                                        bias_full, bias_pad, mask_pad, out);
  else
    win_attn<0><<<B_, 256, 0, stream>>>(x, mask, qkv_bs, proj_b, wq_bf, wp_bf,
                                        bias_full, bias_pad, mask_pad, out);
}